// Round 1
// baseline (6297.356 us; speedup 1.0000x reference)
//
#include <hip/hip_runtime.h>
#include <hip/hip_bf16.h>
#include <math.h>

#define N_NODES 40000
#define N_EDGES 640000
#define F_IN    15
#define HID     128
#define NLAYERS 4
#define NOUT    21

#define FLAG_BIAS 1
#define FLAG_ACC  2
#define FLAG_SILU 4

__device__ __forceinline__ float silu_f(float x) {
    return x / (1.0f + __expf(-x));
}

// ---------------- radial: per-edge squared distance ----------------
__global__ __launch_bounds__(256) void radial_kernel(
    const float* __restrict__ x, const int* __restrict__ erow,
    const int* __restrict__ ecol, float* __restrict__ radial)
{
    int e = blockIdx.x * 256 + threadIdx.x;
    if (e >= N_EDGES) return;
    int r = erow[e], c = ecol[e];
    float dx = x[r*3+0] - x[c*3+0];
    float dy = x[r*3+1] - x[c*3+1];
    float dz = x[r*3+2] - x[c*3+2];
    radial[e] = dx*dx + dy*dy + dz*dz;
}

// ---------------- generic fp32 GEMM: out[M x J] = op(A[M x K] @ W[K x J]) ----
// 256 threads, 32-row x 128-col tile, 4x4 micro-tile per thread.
__global__ __launch_bounds__(256) void gemm_kernel(
    const float* __restrict__ A, int lda,
    const float* __restrict__ W, int ldw,
    const float* __restrict__ bias,
    float* __restrict__ out, int ldout,
    int M, int K, int J, int flags)
{
    __shared__ float s_a[32 * 132];
    const int tid = threadIdx.x;
    const int row0 = blockIdx.x * 32;

    // stage A tile
    for (int idx = tid; idx < 32 * K; idx += 256) {
        int r = (K == 128) ? (idx >> 7) : (idx / K);
        int k = idx - r * K;
        int gr = row0 + r;
        s_a[r * 132 + k] = (gr < M) ? A[(size_t)gr * lda + k] : 0.0f;
    }
    __syncthreads();

    const int jg = tid & 31;
    const int rg = tid >> 5;
    const int j  = jg * 4;
    const int r0 = rg * 4;

    float acc[4][4];
    #pragma unroll
    for (int i = 0; i < 4; i++)
        #pragma unroll
        for (int t = 0; t < 4; t++) acc[i][t] = 0.0f;

    if (j < J) {
        const bool w4ok = ((ldw & 3) == 0) && (j + 4 <= J);
        int k = 0;
        for (; k + 4 <= K; k += 4) {
            float4 av[4];
            #pragma unroll
            for (int i = 0; i < 4; i++)
                av[i] = *(const float4*)&s_a[(r0 + i) * 132 + k];
            #pragma unroll
            for (int kk = 0; kk < 4; kk++) {
                const float* wp = W + (size_t)(k + kk) * ldw + j;
                float4 w4;
                if (w4ok) {
                    w4 = *(const float4*)wp;
                } else {
                    w4.x = (j + 0 < J) ? wp[0] : 0.0f;
                    w4.y = (j + 1 < J) ? wp[1] : 0.0f;
                    w4.z = (j + 2 < J) ? wp[2] : 0.0f;
                    w4.w = (j + 3 < J) ? wp[3] : 0.0f;
                }
                #pragma unroll
                for (int i = 0; i < 4; i++) {
                    float a = ((const float*)&av[i])[kk];
                    acc[i][0] += a * w4.x;
                    acc[i][1] += a * w4.y;
                    acc[i][2] += a * w4.z;
                    acc[i][3] += a * w4.w;
                }
            }
        }
        for (; k < K; k++) {
            const float* wp = W + (size_t)k * ldw + j;
            float w0 = (j + 0 < J) ? wp[0] : 0.0f;
            float w1 = (j + 1 < J) ? wp[1] : 0.0f;
            float w2 = (j + 2 < J) ? wp[2] : 0.0f;
            float w3 = (j + 3 < J) ? wp[3] : 0.0f;
            #pragma unroll
            for (int i = 0; i < 4; i++) {
                float a = s_a[(r0 + i) * 132 + k];
                acc[i][0] += a * w0;
                acc[i][1] += a * w1;
                acc[i][2] += a * w2;
                acc[i][3] += a * w3;
            }
        }
    }

    #pragma unroll
    for (int i = 0; i < 4; i++) {
        int gr = row0 + r0 + i;
        if (gr >= M) continue;
        #pragma unroll
        for (int t = 0; t < 4; t++) {
            int jj = j + t;
            if (jj >= J) continue;
            float v = acc[i][t];
            if (flags & FLAG_BIAS) v += bias[jj];
            if (flags & FLAG_ACC)  v += out[(size_t)gr * ldout + jj];
            if (flags & FLAG_SILU) v = silu_f(v);
            out[(size_t)gr * ldout + jj] = v;
        }
    }
}

// ---------------- fused edge kernel ----------------
// pre1 = P_src[row] + P_tgt[col] + radial*wr + ea@we   (biases folded into P_src)
// ef   = silu(silu(pre1) @ W2 + b2);  atomicAdd into agg[row]
__global__ __launch_bounds__(256) void edge_kernel(
    const float* __restrict__ P,          // [N,256]: [src_proj | tgt_proj]
    const float* __restrict__ radial,     // [E]
    const float* __restrict__ edge_attr,  // [E,4]
    const int* __restrict__ erow, const int* __restrict__ ecol,
    const float* __restrict__ W2,         // [128,128]
    const float* __restrict__ b2,         // [128]
    const float* __restrict__ wr,         // [128]  (ew1 row 256)
    const float* __restrict__ we,         // [4,128] (ew1 rows 257..260)
    float* __restrict__ agg)              // [N,128]
{
    __shared__ float s_ef[32 * 132];
    __shared__ int   s_row[32];

    const int tid  = threadIdx.x;
    const int lane = tid & 63;
    const int w    = tid >> 6;
    const int eb   = blockIdx.x * 32;

    if (tid < 32) s_row[tid] = erow[eb + tid];

    // phase 1: assemble pre1 and silu -> LDS (each wave: one edge per iter)
    #pragma unroll
    for (int it = 0; it < 8; ++it) {
        int et = it * 4 + w;
        int e  = eb + et;
        int r  = erow[e], c = ecol[e];
        float rad = radial[e];
        float ea0 = edge_attr[e*4+0], ea1 = edge_attr[e*4+1];
        float ea2 = edge_attr[e*4+2], ea3 = edge_attr[e*4+3];
        int k = lane * 2;
        float2 ps  = *(const float2*)&P[(size_t)r * 256 + k];
        float2 pt  = *(const float2*)&P[(size_t)c * 256 + 128 + k];
        float2 wrv = *(const float2*)&wr[k];
        float2 w0  = *(const float2*)&we[0*128 + k];
        float2 w1  = *(const float2*)&we[1*128 + k];
        float2 w2v = *(const float2*)&we[2*128 + k];
        float2 w3  = *(const float2*)&we[3*128 + k];
        float v0 = ps.x + pt.x + rad*wrv.x + ea0*w0.x + ea1*w1.x + ea2*w2v.x + ea3*w3.x;
        float v1 = ps.y + pt.y + rad*wrv.y + ea0*w0.y + ea1*w1.y + ea2*w2v.y + ea3*w3.y;
        *(float2*)&s_ef[et * 132 + k] = make_float2(silu_f(v0), silu_f(v1));
    }
    __syncthreads();

    // phase 2: 32x128 @ 128x128 GEMM (W2 streamed through L1)
    const int jg = tid & 31;
    const int rg = tid >> 5;
    const int j  = jg * 4;
    const int e0 = rg * 4;

    float acc[4][4];
    #pragma unroll
    for (int i = 0; i < 4; i++)
        #pragma unroll
        for (int t = 0; t < 4; t++) acc[i][t] = 0.0f;

    for (int k = 0; k < 128; k += 4) {
        float4 av[4];
        #pragma unroll
        for (int i = 0; i < 4; i++)
            av[i] = *(const float4*)&s_ef[(e0 + i) * 132 + k];
        #pragma unroll
        for (int kk = 0; kk < 4; kk++) {
            float4 w4 = *(const float4*)&W2[(size_t)(k + kk) * 128 + j];
            #pragma unroll
            for (int i = 0; i < 4; i++) {
                float a = ((const float*)&av[i])[kk];
                acc[i][0] += a * w4.x;
                acc[i][1] += a * w4.y;
                acc[i][2] += a * w4.z;
                acc[i][3] += a * w4.w;
            }
        }
    }

    // phase 3: silu + scatter-add
    float4 b4 = *(const float4*)&b2[j];
    #pragma unroll
    for (int i = 0; i < 4; i++) {
        int rowIdx = s_row[e0 + i];
        float* dst = agg + (size_t)rowIdx * 128 + j;
        atomicAdd(&dst[0], silu_f(acc[i][0] + b4.x));
        atomicAdd(&dst[1], silu_f(acc[i][1] + b4.y));
        atomicAdd(&dst[2], silu_f(acc[i][2] + b4.z));
        atomicAdd(&dst[3], silu_f(acc[i][3] + b4.w));
    }
}

extern "C" void kernel_launch(void* const* d_in, const int* in_sizes, int n_in,
                              void* d_out, int out_size, void* d_ws, size_t ws_size,
                              hipStream_t stream)
{
    const float* h0       = (const float*)d_in[0];
    const float* x        = (const float*)d_in[1];
    const int*   edges    = (const int*)  d_in[2];
    const float* edge_attr= (const float*)d_in[3];
    const float* emb_w    = (const float*)d_in[4];
    const float* emb_b    = (const float*)d_in[5];
    const float* ew1      = (const float*)d_in[6];
    const float* eb1      = (const float*)d_in[7];
    const float* ew2      = (const float*)d_in[8];
    const float* eb2      = (const float*)d_in[9];
    const float* nw1      = (const float*)d_in[10];
    const float* nb1      = (const float*)d_in[11];
    const float* nw2      = (const float*)d_in[12];
    const float* nb2      = (const float*)d_in[13];
    const float* dw1      = (const float*)d_in[14];
    const float* db1      = (const float*)d_in[15];
    const float* dw2      = (const float*)d_in[16];
    const float* db2      = (const float*)d_in[17];
    const float* gw1      = (const float*)d_in[18];
    const float* gb1      = (const float*)d_in[19];
    const float* gw2      = (const float*)d_in[20];
    const float* gb2      = (const float*)d_in[21];
    float* out = (float*)d_out;

    char* ws = (char*)d_ws;
    const size_t SZ_H = (size_t)N_NODES * HID * 4;      // 20.48 MB
    float* h      = (float*)(ws);
    float* P      = (float*)(ws + SZ_H);                // N x 256
    float* agg    = (float*)(ws + SZ_H * 3);
    float* tmp1   = (float*)(ws + SZ_H * 4);
    float* radial = (float*)(ws + SZ_H * 5);            // E floats

    const int* erow = edges;
    const int* ecol = edges + N_EDGES;

    radial_kernel<<<(N_EDGES + 255) / 256, 256, 0, stream>>>(x, erow, ecol, radial);

    // h = h0 @ emb_w + emb_b
    gemm_kernel<<<(N_NODES + 31) / 32, 256, 0, stream>>>(
        h0, F_IN, emb_w, HID, emb_b, h, HID, N_NODES, F_IN, HID, FLAG_BIAS);

    for (int l = 0; l < NLAYERS; ++l) {
        const float* W1   = ew1 + (size_t)l * 261 * 128;
        const float* b1   = eb1 + l * 128;
        const float* W2   = ew2 + (size_t)l * 128 * 128;
        const float* b2v  = eb2 + l * 128;
        const float* A1   = nw1 + (size_t)l * 271 * 128;
        const float* nb1v = nb1 + l * 128;
        const float* NW2  = nw2 + (size_t)l * 128 * 128;
        const float* nb2v = nb2 + l * 128;

        // node projections: P_src = h@W1[0:128] + b1 ; P_tgt = h@W1[128:256]
        gemm_kernel<<<1250, 256, 0, stream>>>(
            h, HID, W1, HID, b1, P, 256, N_NODES, HID, HID, FLAG_BIAS);
        gemm_kernel<<<1250, 256, 0, stream>>>(
            h, HID, W1 + 128 * 128, HID, nullptr, P + 128, 256, N_NODES, HID, HID, 0);

        hipMemsetAsync(agg, 0, SZ_H, stream);

        edge_kernel<<<N_EDGES / 32, 256, 0, stream>>>(
            P, radial, edge_attr, erow, ecol, W2, b2v,
            W1 + 256 * 128, W1 + 257 * 128, agg);

        // node MLP: tmp1 = silu(h@A + agg@B + h0@C + nb1); h += tmp1@nw2 + nb2
        gemm_kernel<<<1250, 256, 0, stream>>>(
            h, HID, A1, HID, nb1v, tmp1, HID, N_NODES, HID, HID, FLAG_BIAS);
        gemm_kernel<<<1250, 256, 0, stream>>>(
            agg, HID, A1 + 128 * 128, HID, nullptr, tmp1, HID, N_NODES, HID, HID, FLAG_ACC);
        gemm_kernel<<<1250, 256, 0, stream>>>(
            h0, F_IN, A1 + 256 * 128, HID, nullptr, tmp1, HID, N_NODES, F_IN, HID,
            FLAG_ACC | FLAG_SILU);
        gemm_kernel<<<1250, 256, 0, stream>>>(
            tmp1, HID, NW2, HID, nb2v, h, HID, N_NODES, HID, HID, FLAG_BIAS | FLAG_ACC);
    }

    // decoders
    gemm_kernel<<<1250, 256, 0, stream>>>(
        h, HID, dw1, HID, db1, tmp1, HID, N_NODES, HID, HID, FLAG_BIAS | FLAG_SILU);
    gemm_kernel<<<1250, 256, 0, stream>>>(
        tmp1, HID, dw2, HID, db2, h, HID, N_NODES, HID, HID, FLAG_BIAS);
    gemm_kernel<<<1250, 256, 0, stream>>>(
        h, HID, gw1, HID, gb1, tmp1, HID, N_NODES, HID, HID, FLAG_BIAS | FLAG_SILU);
    gemm_kernel<<<1250, 256, 0, stream>>>(
        tmp1, HID, gw2, NOUT, gb2, out, NOUT, N_NODES, HID, NOUT, FLAG_BIAS);
}

// Round 2
// 3494.250 us; speedup vs baseline: 1.8022x; 1.8022x over previous
//
#include <hip/hip_runtime.h>
#include <hip/hip_bf16.h>
#include <math.h>

#define N_NODES 40000
#define N_EDGES 640000
#define F_IN    15
#define HID     128
#define NLAYERS 4
#define NOUT    21

#define FLAG_BIAS 1
#define FLAG_ACC  2
#define FLAG_SILU 4

__device__ __forceinline__ float silu_f(float x) {
    return x / (1.0f + __expf(-x));
}

// ---------------- radial: per-edge squared distance ----------------
__global__ __launch_bounds__(256) void radial_kernel(
    const float* __restrict__ x, const int* __restrict__ erow,
    const int* __restrict__ ecol, float* __restrict__ radial)
{
    int e = blockIdx.x * 256 + threadIdx.x;
    if (e >= N_EDGES) return;
    int r = erow[e], c = ecol[e];
    float dx = x[r*3+0] - x[c*3+0];
    float dy = x[r*3+1] - x[c*3+1];
    float dz = x[r*3+2] - x[c*3+2];
    radial[e] = dx*dx + dy*dy + dz*dz;
}

// ---------------- CSR build: histogram, scan, scatter ----------------
__global__ __launch_bounds__(256) void hist_kernel(
    const int* __restrict__ erow, int* __restrict__ cnt)
{
    int e = blockIdx.x * 256 + threadIdx.x;
    if (e < N_EDGES) atomicAdd(&cnt[erow[e]], 1);
}

// single-block exclusive scan: rowptr[0]=0, rowptr[i+1]=sum(cnt[0..i])
__global__ __launch_bounds__(1024) void scan_kernel(
    const int* __restrict__ cnt, int* __restrict__ rowptr)
{
    __shared__ int s[1024];
    __shared__ int carry_s;
    const int tid = threadIdx.x;
    if (tid == 0) { carry_s = 0; rowptr[0] = 0; }
    __syncthreads();
    for (int base = 0; base < N_NODES; base += 1024) {
        int i = base + tid;
        int v = (i < N_NODES) ? cnt[i] : 0;
        s[tid] = v;
        __syncthreads();
        // Hillis-Steele inclusive scan
        for (int off = 1; off < 1024; off <<= 1) {
            int t = (tid >= off) ? s[tid - off] : 0;
            __syncthreads();
            s[tid] += t;
            __syncthreads();
        }
        int c = carry_s;
        if (i < N_NODES) rowptr[i + 1] = c + s[tid];
        __syncthreads();
        if (tid == 1023) carry_s = c + s[1023];
        __syncthreads();
    }
}

// scatter edges into row-sorted order, permuting payloads
__global__ __launch_bounds__(256) void scatter_kernel(
    const int* __restrict__ erow, const int* __restrict__ ecol,
    const float* __restrict__ radial, const float* __restrict__ edge_attr,
    const int* __restrict__ rowptr, int* __restrict__ fill,
    int* __restrict__ srow, int* __restrict__ scol,
    float* __restrict__ srad, float* __restrict__ sea)
{
    int e = blockIdx.x * 256 + threadIdx.x;
    if (e >= N_EDGES) return;
    int r = erow[e];
    int pos = rowptr[r] + atomicAdd(&fill[r], 1);
    srow[pos] = r;
    scol[pos] = ecol[e];
    srad[pos] = radial[e];
    float4 ea = *(const float4*)&edge_attr[(size_t)e * 4];
    *(float4*)&sea[(size_t)pos * 4] = ea;
}

// ---------------- generic fp32 GEMM: out[M x J] = op(A[M x K] @ W[K x J]) ----
__global__ __launch_bounds__(256) void gemm_kernel(
    const float* __restrict__ A, int lda,
    const float* __restrict__ W, int ldw,
    const float* __restrict__ bias,
    float* __restrict__ out, int ldout,
    int M, int K, int J, int flags)
{
    __shared__ float s_a[32 * 132];
    const int tid = threadIdx.x;
    const int row0 = blockIdx.x * 32;

    for (int idx = tid; idx < 32 * K; idx += 256) {
        int r = (K == 128) ? (idx >> 7) : (idx / K);
        int k = idx - r * K;
        int gr = row0 + r;
        s_a[r * 132 + k] = (gr < M) ? A[(size_t)gr * lda + k] : 0.0f;
    }
    __syncthreads();

    const int jg = tid & 31;
    const int rg = tid >> 5;
    const int j  = jg * 4;
    const int r0 = rg * 4;

    float acc[4][4];
    #pragma unroll
    for (int i = 0; i < 4; i++)
        #pragma unroll
        for (int t = 0; t < 4; t++) acc[i][t] = 0.0f;

    if (j < J) {
        const bool w4ok = ((ldw & 3) == 0) && (j + 4 <= J);
        int k = 0;
        for (; k + 4 <= K; k += 4) {
            float4 av[4];
            #pragma unroll
            for (int i = 0; i < 4; i++)
                av[i] = *(const float4*)&s_a[(r0 + i) * 132 + k];
            #pragma unroll
            for (int kk = 0; kk < 4; kk++) {
                const float* wp = W + (size_t)(k + kk) * ldw + j;
                float4 w4;
                if (w4ok) {
                    w4 = *(const float4*)wp;
                } else {
                    w4.x = (j + 0 < J) ? wp[0] : 0.0f;
                    w4.y = (j + 1 < J) ? wp[1] : 0.0f;
                    w4.z = (j + 2 < J) ? wp[2] : 0.0f;
                    w4.w = (j + 3 < J) ? wp[3] : 0.0f;
                }
                #pragma unroll
                for (int i = 0; i < 4; i++) {
                    float a = ((const float*)&av[i])[kk];
                    acc[i][0] += a * w4.x;
                    acc[i][1] += a * w4.y;
                    acc[i][2] += a * w4.z;
                    acc[i][3] += a * w4.w;
                }
            }
        }
        for (; k < K; k++) {
            const float* wp = W + (size_t)k * ldw + j;
            float w0 = (j + 0 < J) ? wp[0] : 0.0f;
            float w1 = (j + 1 < J) ? wp[1] : 0.0f;
            float w2 = (j + 2 < J) ? wp[2] : 0.0f;
            float w3 = (j + 3 < J) ? wp[3] : 0.0f;
            #pragma unroll
            for (int i = 0; i < 4; i++) {
                float a = s_a[(r0 + i) * 132 + k];
                acc[i][0] += a * w0;
                acc[i][1] += a * w1;
                acc[i][2] += a * w2;
                acc[i][3] += a * w3;
            }
        }
    }

    #pragma unroll
    for (int i = 0; i < 4; i++) {
        int gr = row0 + r0 + i;
        if (gr >= M) continue;
        #pragma unroll
        for (int t = 0; t < 4; t++) {
            int jj = j + t;
            if (jj >= J) continue;
            float v = acc[i][t];
            if (flags & FLAG_BIAS) v += bias[jj];
            if (flags & FLAG_ACC)  v += out[(size_t)gr * ldout + jj];
            if (flags & FLAG_SILU) v = silu_f(v);
            out[(size_t)gr * ldout + jj] = v;
        }
    }
}

// ---------------- fused edge kernel (row-sorted edges) ----------------
// pre1 = P_src[row] + P_tgt[col] + radial*wr + ea@we   (b1 folded into P_src)
// ef   = silu(silu(pre1) @ W2 + b2); segmented-reduce over equal rows; atomic per segment
__global__ __launch_bounds__(256) void edge_kernel(
    const float* __restrict__ P,          // [N,256]: [src_proj | tgt_proj]
    const int* __restrict__ srow, const int* __restrict__ scol,
    const float* __restrict__ srad, const float* __restrict__ sea,
    const float* __restrict__ W2,         // [128,128]
    const float* __restrict__ b2,         // [128]
    const float* __restrict__ wr,         // [128]  (ew1 row 256)
    const float* __restrict__ we,         // [4,128] (ew1 rows 257..260)
    float* __restrict__ agg)              // [N,128]
{
    __shared__ float s_ef[32 * 132];
    __shared__ int   s_row[32];
    __shared__ int   s_segstart[33];
    __shared__ int   s_nseg;

    const int tid  = threadIdx.x;
    const int lane = tid & 63;
    const int w    = tid >> 6;
    const int p0b  = blockIdx.x * 32;

    if (tid < 32) s_row[tid] = srow[p0b + tid];

    // phase 1: assemble pre1, silu -> LDS (each wave: one edge per iter)
    #pragma unroll
    for (int it = 0; it < 8; ++it) {
        int et = it * 4 + w;
        int p  = p0b + et;
        int r  = srow[p], c = scol[p];
        float rad = srad[p];
        float4 ea = *(const float4*)&sea[(size_t)p * 4];
        int k = lane * 2;
        float2 ps  = *(const float2*)&P[(size_t)r * 256 + k];
        float2 pt  = *(const float2*)&P[(size_t)c * 256 + 128 + k];
        float2 wrv = *(const float2*)&wr[k];
        float2 w0  = *(const float2*)&we[0*128 + k];
        float2 w1  = *(const float2*)&we[1*128 + k];
        float2 w2v = *(const float2*)&we[2*128 + k];
        float2 w3  = *(const float2*)&we[3*128 + k];
        float v0 = ps.x + pt.x + rad*wrv.x + ea.x*w0.x + ea.y*w1.x + ea.z*w2v.x + ea.w*w3.x;
        float v1 = ps.y + pt.y + rad*wrv.y + ea.x*w0.y + ea.y*w1.y + ea.z*w2v.y + ea.w*w3.y;
        *(float2*)&s_ef[et * 132 + k] = make_float2(silu_f(v0), silu_f(v1));
    }
    // segment boundaries over the 32 sorted rows (serial by thread 0, cheap)
    __syncthreads();
    if (tid == 0) {
        int ns = 0, prev = -1;
        #pragma unroll 1
        for (int p = 0; p < 32; ++p) {
            int r = s_row[p];
            if (r != prev) { s_segstart[ns++] = p; prev = r; }
        }
        s_segstart[ns] = 32;
        s_nseg = ns;
    }

    // phase 2: 32x128 @ 128x128 GEMM (W2 streamed through L1)
    const int jg = tid & 31;
    const int rg = tid >> 5;
    const int j  = jg * 4;
    const int e0 = rg * 4;

    float acc[4][4];
    #pragma unroll
    for (int i = 0; i < 4; i++)
        #pragma unroll
        for (int t = 0; t < 4; t++) acc[i][t] = 0.0f;

    for (int k = 0; k < 128; k += 4) {
        float4 av[4];
        #pragma unroll
        for (int i = 0; i < 4; i++)
            av[i] = *(const float4*)&s_ef[(e0 + i) * 132 + k];
        #pragma unroll
        for (int kk = 0; kk < 4; kk++) {
            float4 w4 = *(const float4*)&W2[(size_t)(k + kk) * 128 + j];
            #pragma unroll
            for (int i = 0; i < 4; i++) {
                float a = ((const float*)&av[i])[kk];
                acc[i][0] += a * w4.x;
                acc[i][1] += a * w4.y;
                acc[i][2] += a * w4.z;
                acc[i][3] += a * w4.w;
            }
        }
    }
    __syncthreads();   // everyone done reading s_ef

    // phase 2b: silu(acc + b2) back into LDS
    float4 b4 = *(const float4*)&b2[j];
    #pragma unroll
    for (int i = 0; i < 4; i++) {
        s_ef[(e0 + i) * 132 + j + 0] = silu_f(acc[i][0] + b4.x);
        s_ef[(e0 + i) * 132 + j + 1] = silu_f(acc[i][1] + b4.y);
        s_ef[(e0 + i) * 132 + j + 2] = silu_f(acc[i][2] + b4.z);
        s_ef[(e0 + i) * 132 + j + 3] = silu_f(acc[i][3] + b4.w);
    }
    __syncthreads();

    // phase 3: segmented reduction + one atomic quad per segment
    const int nseg = s_nseg;
    for (int s = rg; s < nseg; s += 8) {
        int sp0 = s_segstart[s], sp1 = s_segstart[s + 1];
        float v0 = 0.f, v1 = 0.f, v2 = 0.f, v3 = 0.f;
        for (int p = sp0; p < sp1; ++p) {
            float4 q = *(const float4*)&s_ef[p * 132 + j];
            v0 += q.x; v1 += q.y; v2 += q.z; v3 += q.w;
        }
        float* dst = agg + (size_t)s_row[sp0] * 128 + j;
        atomicAdd(&dst[0], v0);
        atomicAdd(&dst[1], v1);
        atomicAdd(&dst[2], v2);
        atomicAdd(&dst[3], v3);
    }
}

extern "C" void kernel_launch(void* const* d_in, const int* in_sizes, int n_in,
                              void* d_out, int out_size, void* d_ws, size_t ws_size,
                              hipStream_t stream)
{
    const float* h0       = (const float*)d_in[0];
    const float* x        = (const float*)d_in[1];
    const int*   edges    = (const int*)  d_in[2];
    const float* edge_attr= (const float*)d_in[3];
    const float* emb_w    = (const float*)d_in[4];
    const float* emb_b    = (const float*)d_in[5];
    const float* ew1      = (const float*)d_in[6];
    const float* eb1      = (const float*)d_in[7];
    const float* ew2      = (const float*)d_in[8];
    const float* eb2      = (const float*)d_in[9];
    const float* nw1      = (const float*)d_in[10];
    const float* nb1      = (const float*)d_in[11];
    const float* nw2      = (const float*)d_in[12];
    const float* nb2      = (const float*)d_in[13];
    const float* dw1      = (const float*)d_in[14];
    const float* db1      = (const float*)d_in[15];
    const float* dw2      = (const float*)d_in[16];
    const float* db2      = (const float*)d_in[17];
    const float* gw1      = (const float*)d_in[18];
    const float* gb1      = (const float*)d_in[19];
    const float* gw2      = (const float*)d_in[20];
    const float* gb2      = (const float*)d_in[21];
    float* out = (float*)d_out;

    char* ws = (char*)d_ws;
    const size_t SZ_H = (size_t)N_NODES * HID * 4;      // 20.48 MB
    const size_t SZ_E = (size_t)N_EDGES * 4;            // 2.56 MB
    float* h      = (float*)(ws);
    float* P      = (float*)(ws + SZ_H);                // N x 256
    float* agg    = (float*)(ws + SZ_H * 3);
    float* tmp1   = (float*)(ws + SZ_H * 4);
    float* radial = (float*)(ws + SZ_H * 5);
    int*   s_row  = (int*)  (ws + SZ_H * 5 + SZ_E);
    int*   s_col  = (int*)  (ws + SZ_H * 5 + SZ_E * 2);
    float* s_rad  = (float*)(ws + SZ_H * 5 + SZ_E * 3);
    float* s_ea   = (float*)(ws + SZ_H * 5 + SZ_E * 4); // E x 4
    int*   rowptr = (int*)  (ws + SZ_H * 5 + SZ_E * 8);
    int*   cnt    = (int*)  (ws + SZ_H * 5 + SZ_E * 8 + (N_NODES + 64) * 4);

    const int* erow = edges;
    const int* ecol = edges + N_EDGES;

    radial_kernel<<<N_EDGES / 256, 256, 0, stream>>>(x, erow, ecol, radial);

    // ---- CSR build (edges constant across layers) ----
    hipMemsetAsync(cnt, 0, N_NODES * 4, stream);
    hist_kernel<<<N_EDGES / 256, 256, 0, stream>>>(erow, cnt);
    scan_kernel<<<1, 1024, 0, stream>>>(cnt, rowptr);
    hipMemsetAsync(cnt, 0, N_NODES * 4, stream);  // reuse as fill counters
    scatter_kernel<<<N_EDGES / 256, 256, 0, stream>>>(
        erow, ecol, radial, edge_attr, rowptr, cnt, s_row, s_col, s_rad, s_ea);

    // h = h0 @ emb_w + emb_b
    gemm_kernel<<<(N_NODES + 31) / 32, 256, 0, stream>>>(
        h0, F_IN, emb_w, HID, emb_b, h, HID, N_NODES, F_IN, HID, FLAG_BIAS);

    for (int l = 0; l < NLAYERS; ++l) {
        const float* W1   = ew1 + (size_t)l * 261 * 128;
        const float* b1   = eb1 + l * 128;
        const float* W2   = ew2 + (size_t)l * 128 * 128;
        const float* b2v  = eb2 + l * 128;
        const float* A1   = nw1 + (size_t)l * 271 * 128;
        const float* nb1v = nb1 + l * 128;
        const float* NW2  = nw2 + (size_t)l * 128 * 128;
        const float* nb2v = nb2 + l * 128;

        // node projections: P_src = h@W1[0:128] + b1 ; P_tgt = h@W1[128:256]
        gemm_kernel<<<1250, 256, 0, stream>>>(
            h, HID, W1, HID, b1, P, 256, N_NODES, HID, HID, FLAG_BIAS);
        gemm_kernel<<<1250, 256, 0, stream>>>(
            h, HID, W1 + 128 * 128, HID, nullptr, P + 128, 256, N_NODES, HID, HID, 0);

        hipMemsetAsync(agg, 0, SZ_H, stream);

        edge_kernel<<<N_EDGES / 32, 256, 0, stream>>>(
            P, s_row, s_col, s_rad, s_ea, W2, b2v,
            W1 + 256 * 128, W1 + 257 * 128, agg);

        // node MLP: tmp1 = silu(h@A + agg@B + h0@C + nb1); h += tmp1@nw2 + nb2
        gemm_kernel<<<1250, 256, 0, stream>>>(
            h, HID, A1, HID, nb1v, tmp1, HID, N_NODES, HID, HID, FLAG_BIAS);
        gemm_kernel<<<1250, 256, 0, stream>>>(
            agg, HID, A1 + 128 * 128, HID, nullptr, tmp1, HID, N_NODES, HID, HID, FLAG_ACC);
        gemm_kernel<<<1250, 256, 0, stream>>>(
            h0, F_IN, A1 + 256 * 128, HID, nullptr, tmp1, HID, N_NODES, F_IN, HID,
            FLAG_ACC | FLAG_SILU);
        gemm_kernel<<<1250, 256, 0, stream>>>(
            tmp1, HID, NW2, HID, nb2v, h, HID, N_NODES, HID, HID, FLAG_BIAS | FLAG_ACC);
    }

    // decoders
    gemm_kernel<<<1250, 256, 0, stream>>>(
        h, HID, dw1, HID, db1, tmp1, HID, N_NODES, HID, HID, FLAG_BIAS | FLAG_SILU);
    gemm_kernel<<<1250, 256, 0, stream>>>(
        tmp1, HID, dw2, HID, db2, h, HID, N_NODES, HID, HID, FLAG_BIAS);
    gemm_kernel<<<1250, 256, 0, stream>>>(
        h, HID, gw1, HID, gb1, tmp1, HID, N_NODES, HID, HID, FLAG_BIAS | FLAG_SILU);
    gemm_kernel<<<1250, 256, 0, stream>>>(
        tmp1, HID, gw2, NOUT, gb2, out, NOUT, N_NODES, HID, NOUT, FLAG_BIAS);
}

// Round 3
// 2131.270 us; speedup vs baseline: 2.9547x; 1.6395x over previous
//
#include <hip/hip_runtime.h>
#include <hip/hip_bf16.h>
#include <math.h>

#define N_NODES 40000
#define N_EDGES 640000
#define F_IN    15
#define HID     128
#define NLAYERS 4
#define NOUT    21

#define FLAG_BIAS 1
#define FLAG_ACC  2
#define FLAG_SILU 4

__device__ __forceinline__ float silu_f(float x) {
    return x / (1.0f + __expf(-x));
}

// ---------------- radial: per-edge squared distance ----------------
__global__ __launch_bounds__(256) void radial_kernel(
    const float* __restrict__ x, const int* __restrict__ erow,
    const int* __restrict__ ecol, float* __restrict__ radial)
{
    int e = blockIdx.x * 256 + threadIdx.x;
    if (e >= N_EDGES) return;
    int r = erow[e], c = ecol[e];
    float dx = x[r*3+0] - x[c*3+0];
    float dy = x[r*3+1] - x[c*3+1];
    float dz = x[r*3+2] - x[c*3+2];
    radial[e] = dx*dx + dy*dy + dz*dz;
}

// ---------------- CSR build ----------------
__global__ __launch_bounds__(256) void hist_kernel(
    const int* __restrict__ erow, int* __restrict__ cnt)
{
    int e = blockIdx.x * 256 + threadIdx.x;
    if (e < N_EDGES) atomicAdd(&cnt[erow[e]], 1);
}

__global__ __launch_bounds__(1024) void scan_kernel(
    const int* __restrict__ cnt, int* __restrict__ rowptr)
{
    __shared__ int s[1024];
    __shared__ int carry_s;
    const int tid = threadIdx.x;
    if (tid == 0) { carry_s = 0; rowptr[0] = 0; }
    __syncthreads();
    for (int base = 0; base < N_NODES; base += 1024) {
        int i = base + tid;
        int v = (i < N_NODES) ? cnt[i] : 0;
        s[tid] = v;
        __syncthreads();
        for (int off = 1; off < 1024; off <<= 1) {
            int t = (tid >= off) ? s[tid - off] : 0;
            __syncthreads();
            s[tid] += t;
            __syncthreads();
        }
        int c = carry_s;
        if (i < N_NODES) rowptr[i + 1] = c + s[tid];
        __syncthreads();
        if (tid == 1023) carry_s = c + s[1023];
        __syncthreads();
    }
}

__global__ __launch_bounds__(256) void scatter_kernel(
    const int* __restrict__ erow, const int* __restrict__ ecol,
    const float* __restrict__ radial, const float* __restrict__ edge_attr,
    const int* __restrict__ rowptr, int* __restrict__ fill,
    int* __restrict__ srow, int* __restrict__ scol,
    float* __restrict__ srad, float* __restrict__ sea)
{
    int e = blockIdx.x * 256 + threadIdx.x;
    if (e >= N_EDGES) return;
    int r = erow[e];
    int pos = rowptr[r] + atomicAdd(&fill[r], 1);
    srow[pos] = r;
    scol[pos] = ecol[e];
    srad[pos] = radial[e];
    float4 ea = *(const float4*)&edge_attr[(size_t)e * 4];
    *(float4*)&sea[(size_t)pos * 4] = ea;
}

// ---------------- zero the agg half of hb ----------------
__global__ __launch_bounds__(256) void zero_agg_kernel(float* __restrict__ hb)
{
    int idx = blockIdx.x * 256 + threadIdx.x;     // one float4 each
    int row = idx >> 5, c4 = (idx & 31) * 4;
    *(float4*)&hb[(size_t)row * 256 + 128 + c4] = make_float4(0.f, 0.f, 0.f, 0.f);
}

// ---------------- generic fp32 GEMM (32-row tile) for K=15 / J=21 cases ----
__global__ __launch_bounds__(256) void gemm_kernel(
    const float* __restrict__ A, int lda,
    const float* __restrict__ W, int ldw,
    const float* __restrict__ bias,
    float* __restrict__ out, int ldout,
    int M, int K, int J, int flags)
{
    __shared__ float s_a[32 * 132];
    const int tid = threadIdx.x;
    const int row0 = blockIdx.x * 32;

    for (int idx = tid; idx < 32 * K; idx += 256) {
        int r = (K == 128) ? (idx >> 7) : (idx / K);
        int k = idx - r * K;
        int gr = row0 + r;
        s_a[r * 132 + k] = (gr < M) ? A[(size_t)gr * lda + k] : 0.0f;
    }
    __syncthreads();

    const int jg = tid & 31;
    const int rg = tid >> 5;
    const int j  = jg * 4;
    const int r0 = rg * 4;

    float acc[4][4] = {};

    if (j < J) {
        const bool w4ok = ((ldw & 3) == 0) && (j + 4 <= J);
        int k = 0;
        for (; k + 4 <= K; k += 4) {
            float4 av[4];
            #pragma unroll
            for (int i = 0; i < 4; i++)
                av[i] = *(const float4*)&s_a[(r0 + i) * 132 + k];
            #pragma unroll
            for (int kk = 0; kk < 4; kk++) {
                const float* wp = W + (size_t)(k + kk) * ldw + j;
                float4 w4;
                if (w4ok) {
                    w4 = *(const float4*)wp;
                } else {
                    w4.x = (j + 0 < J) ? wp[0] : 0.0f;
                    w4.y = (j + 1 < J) ? wp[1] : 0.0f;
                    w4.z = (j + 2 < J) ? wp[2] : 0.0f;
                    w4.w = (j + 3 < J) ? wp[3] : 0.0f;
                }
                #pragma unroll
                for (int i = 0; i < 4; i++) {
                    float a = ((const float*)&av[i])[kk];
                    acc[i][0] += a * w4.x;
                    acc[i][1] += a * w4.y;
                    acc[i][2] += a * w4.z;
                    acc[i][3] += a * w4.w;
                }
            }
        }
        for (; k < K; k++) {
            const float* wp = W + (size_t)k * ldw + j;
            float w0 = (j + 0 < J) ? wp[0] : 0.0f;
            float w1 = (j + 1 < J) ? wp[1] : 0.0f;
            float w2 = (j + 2 < J) ? wp[2] : 0.0f;
            float w3 = (j + 3 < J) ? wp[3] : 0.0f;
            #pragma unroll
            for (int i = 0; i < 4; i++) {
                float a = s_a[(r0 + i) * 132 + k];
                acc[i][0] += a * w0;
                acc[i][1] += a * w1;
                acc[i][2] += a * w2;
                acc[i][3] += a * w3;
            }
        }
    }

    #pragma unroll
    for (int i = 0; i < 4; i++) {
        int gr = row0 + r0 + i;
        if (gr >= M) continue;
        #pragma unroll
        for (int t = 0; t < 4; t++) {
            int jj = j + t;
            if (jj >= J) continue;
            float v = acc[i][t];
            if (flags & FLAG_BIAS) v += bias[jj];
            if (flags & FLAG_ACC)  v += out[(size_t)gr * ldout + jj];
            if (flags & FLAG_SILU) v = silu_f(v);
            out[(size_t)gr * ldout + jj] = v;
        }
    }
}

// ---------------- 64-row x 128-col fp32 GEMM core ----------------
// K in {128, 256} (staged in 128-chunks). Optional A2[64 x 15] epilogue using
// W rows [K .. K+15). M assumed divisible by 64 (40000 = 625*64).
__device__ __forceinline__ void gemm64_core(
    float* s_a,
    const float* __restrict__ A, int lda,
    const float* __restrict__ W,
    const float* __restrict__ bias,
    const float* __restrict__ A2,
    float* __restrict__ out, int ldout,
    int K, int flags, int row0)
{
    const int tid = threadIdx.x;
    const int jg = tid & 31, rg = tid >> 5;
    const int j = jg * 4, r0 = rg * 8;

    float acc[8][4] = {};

    for (int kc = 0; kc < K; kc += 128) {
        __syncthreads();
        #pragma unroll
        for (int i = 0; i < 8; ++i) {
            int idx = tid + i * 256;
            int row = idx >> 5, c4 = (idx & 31) * 4;
            *(float4*)&s_a[row * 132 + c4] =
                *(const float4*)&A[(size_t)(row0 + row) * lda + kc + c4];
        }
        __syncthreads();
        for (int k = 0; k < 128; k += 4) {
            float4 av[8];
            #pragma unroll
            for (int i = 0; i < 8; ++i)
                av[i] = *(const float4*)&s_a[(r0 + i) * 132 + k];
            #pragma unroll
            for (int kk = 0; kk < 4; ++kk) {
                float4 w4 = *(const float4*)&W[(size_t)(kc + k + kk) * 128 + j];
                #pragma unroll
                for (int i = 0; i < 8; ++i) {
                    float a = ((const float*)&av[i])[kk];
                    acc[i][0] += a * w4.x;
                    acc[i][1] += a * w4.y;
                    acc[i][2] += a * w4.z;
                    acc[i][3] += a * w4.w;
                }
            }
        }
    }

    if (A2) {  // h0 epilogue: K2 = 15, W rows K..K+14
        __syncthreads();
        for (int idx = tid; idx < 64 * 16; idx += 256) {
            int row = idx >> 4, c = idx & 15;
            s_a[idx] = (c < F_IN) ? A2[(size_t)(row0 + row) * F_IN + c] : 0.0f;
        }
        __syncthreads();
        #pragma unroll 1
        for (int k = 0; k < F_IN; ++k) {
            float4 w4 = *(const float4*)&W[(size_t)(K + k) * 128 + j];
            #pragma unroll
            for (int i = 0; i < 8; ++i) {
                float a = s_a[(r0 + i) * 16 + k];
                acc[i][0] += a * w4.x;
                acc[i][1] += a * w4.y;
                acc[i][2] += a * w4.z;
                acc[i][3] += a * w4.w;
            }
        }
    }

    float4 b4 = (flags & FLAG_BIAS) ? *(const float4*)&bias[j]
                                    : make_float4(0.f, 0.f, 0.f, 0.f);
    #pragma unroll
    for (int i = 0; i < 8; ++i) {
        float* op = &out[(size_t)(row0 + r0 + i) * ldout + j];
        float v0 = acc[i][0] + b4.x, v1 = acc[i][1] + b4.y;
        float v2 = acc[i][2] + b4.z, v3 = acc[i][3] + b4.w;
        if (flags & FLAG_ACC) {
            float4 o = *(const float4*)op;
            v0 += o.x; v1 += o.y; v2 += o.z; v3 += o.w;
        }
        if (flags & FLAG_SILU) { v0 = silu_f(v0); v1 = silu_f(v1);
                                 v2 = silu_f(v2); v3 = silu_f(v3); }
        *(float4*)op = make_float4(v0, v1, v2, v3);
    }
}

__global__ __launch_bounds__(256) void gemm64_kernel(
    const float* __restrict__ A, int lda, const float* __restrict__ W,
    const float* __restrict__ bias, const float* __restrict__ A2,
    float* __restrict__ out, int ldout, int K, int flags)
{
    __shared__ float s_a[64 * 132];
    gemm64_core(s_a, A, lda, W, bias, A2, out, ldout, K, flags, blockIdx.x * 64);
}

// P[:,0:128] = h@W1a + b1 ; P[:,128:256] = h@W1b   (one dispatch, grid.y=2)
__global__ __launch_bounds__(256) void proj_kernel(
    const float* __restrict__ hb, const float* __restrict__ W1,
    const float* __restrict__ b1, float* __restrict__ P)
{
    __shared__ float s_a[64 * 132];
    int y = blockIdx.y;
    gemm64_core(s_a, hb, 256, W1 + y * 128 * 128, b1, nullptr,
                P + y * 128, 256, 128, y ? 0 : FLAG_BIAS, blockIdx.x * 64);
}

// ---------------- fused edge kernel: 64 row-sorted edges per block ---------
__global__ __launch_bounds__(256) void edge_kernel(
    const float* __restrict__ P,
    const int* __restrict__ srow, const int* __restrict__ scol,
    const float* __restrict__ srad, const float* __restrict__ sea,
    const float* __restrict__ W2, const float* __restrict__ b2,
    const float* __restrict__ wr, const float* __restrict__ we,
    float* __restrict__ hb)
{
    __shared__ float s_ef[64 * 128];
    __shared__ int   s_row[64];
    __shared__ int   s_col[64];
    __shared__ float s_rad[64];
    __shared__ float s_ea4[64 * 4];
    __shared__ int   s_segstart[66];
    __shared__ int   s_nseg;

    const int tid  = threadIdx.x;
    const int lane = tid & 63;
    const int w    = tid >> 6;
    const int p0   = blockIdx.x * 64;

    if (tid < 64) {
        s_row[tid] = srow[p0 + tid];
        s_col[tid] = scol[p0 + tid];
        s_rad[tid] = srad[p0 + tid];
        *(float4*)&s_ea4[tid * 4] = *(const float4*)&sea[(size_t)(p0 + tid) * 4];
    }
    __syncthreads();

    // segment boundaries via ballot (wave 0 only)
    if (tid < 64) {
        bool flag = (tid == 0) || (s_row[tid] != s_row[tid - 1]);
        unsigned long long mask = __ballot(flag);
        int idx = __popcll(mask & ((1ull << tid) - 1));
        if (flag) s_segstart[idx] = tid;
        if (tid == 0) {
            int ns = __popcll(mask);
            s_nseg = ns;
            s_segstart[ns] = 64;
        }
    }

    // phase 1: pre1 = P_src[row] + P_tgt[col] + rad*wr + ea@we ; silu -> LDS
    const int k2 = lane * 2;
    const float2 wrv = *(const float2*)&wr[k2];
    const float2 wa0 = *(const float2*)&we[0 * 128 + k2];
    const float2 wa1 = *(const float2*)&we[1 * 128 + k2];
    const float2 wa2 = *(const float2*)&we[2 * 128 + k2];
    const float2 wa3 = *(const float2*)&we[3 * 128 + k2];
    #pragma unroll 4
    for (int it = 0; it < 16; ++it) {
        int et = it * 4 + w;
        int r = s_row[et], c = s_col[et];
        float rad = s_rad[et];
        float ea0 = s_ea4[et*4+0], ea1 = s_ea4[et*4+1];
        float ea2 = s_ea4[et*4+2], ea3 = s_ea4[et*4+3];
        float2 ps = *(const float2*)&P[(size_t)r * 256 + k2];
        float2 pt = *(const float2*)&P[(size_t)c * 256 + 128 + k2];
        float v0 = ps.x + pt.x + rad*wrv.x + ea0*wa0.x + ea1*wa1.x + ea2*wa2.x + ea3*wa3.x;
        float v1 = ps.y + pt.y + rad*wrv.y + ea0*wa0.y + ea1*wa1.y + ea2*wa2.y + ea3*wa3.y;
        *(float2*)&s_ef[et * 128 + k2] = make_float2(silu_f(v0), silu_f(v1));
    }
    __syncthreads();

    // phase 2: 64x128 @ 128x128 (W2 streamed, L2-hot)
    const int jg = tid & 31, rg = tid >> 5;
    const int j = jg * 4, e0 = rg * 8;

    float acc[8][4] = {};
    for (int k = 0; k < 128; k += 4) {
        float4 av[8];
        #pragma unroll
        for (int i = 0; i < 8; ++i)
            av[i] = *(const float4*)&s_ef[(e0 + i) * 128 + k];
        #pragma unroll
        for (int kk = 0; kk < 4; ++kk) {
            float4 w4 = *(const float4*)&W2[(size_t)(k + kk) * 128 + j];
            #pragma unroll
            for (int i = 0; i < 8; ++i) {
                float a = ((const float*)&av[i])[kk];
                acc[i][0] += a * w4.x;
                acc[i][1] += a * w4.y;
                acc[i][2] += a * w4.z;
                acc[i][3] += a * w4.w;
            }
        }
    }
    __syncthreads();   // all reads of s_ef done

    // phase 2b: silu(acc + b2) back into LDS
    float4 b4 = *(const float4*)&b2[j];
    #pragma unroll
    for (int i = 0; i < 8; ++i) {
        *(float4*)&s_ef[(e0 + i) * 128 + j] = make_float4(
            silu_f(acc[i][0] + b4.x), silu_f(acc[i][1] + b4.y),
            silu_f(acc[i][2] + b4.z), silu_f(acc[i][3] + b4.w));
    }
    __syncthreads();

    // phase 3: segmented reduce; interior rows -> plain store, boundary -> atomics
    const int nseg = s_nseg;
    for (int s = rg; s < nseg; s += 8) {
        int sp0 = s_segstart[s], sp1 = s_segstart[s + 1];
        float v0 = 0.f, v1 = 0.f, v2 = 0.f, v3 = 0.f;
        for (int p = sp0; p < sp1; ++p) {
            float4 q = *(const float4*)&s_ef[p * 128 + j];
            v0 += q.x; v1 += q.y; v2 += q.z; v3 += q.w;
        }
        int rowId = s_row[sp0];
        bool interior = true;
        if (sp0 == 0 && p0 > 0 && srow[p0 - 1] == rowId) interior = false;
        if (sp1 == 64 && p0 + 64 < N_EDGES && srow[p0 + 64] == rowId) interior = false;
        float* dst = &hb[(size_t)rowId * 256 + 128 + j];
        if (interior) {
            *(float4*)dst = make_float4(v0, v1, v2, v3);
        } else {
            atomicAdd(&dst[0], v0); atomicAdd(&dst[1], v1);
            atomicAdd(&dst[2], v2); atomicAdd(&dst[3], v3);
        }
    }
}

extern "C" void kernel_launch(void* const* d_in, const int* in_sizes, int n_in,
                              void* d_out, int out_size, void* d_ws, size_t ws_size,
                              hipStream_t stream)
{
    const float* h0       = (const float*)d_in[0];
    const float* x        = (const float*)d_in[1];
    const int*   edges    = (const int*)  d_in[2];
    const float* edge_attr= (const float*)d_in[3];
    const float* emb_w    = (const float*)d_in[4];
    const float* emb_b    = (const float*)d_in[5];
    const float* ew1      = (const float*)d_in[6];
    const float* eb1      = (const float*)d_in[7];
    const float* ew2      = (const float*)d_in[8];
    const float* eb2      = (const float*)d_in[9];
    const float* nw1      = (const float*)d_in[10];
    const float* nb1      = (const float*)d_in[11];
    const float* nw2      = (const float*)d_in[12];
    const float* nb2      = (const float*)d_in[13];
    const float* dw1      = (const float*)d_in[14];
    const float* db1      = (const float*)d_in[15];
    const float* dw2      = (const float*)d_in[16];
    const float* db2      = (const float*)d_in[17];
    const float* gw1      = (const float*)d_in[18];
    const float* gb1      = (const float*)d_in[19];
    const float* gw2      = (const float*)d_in[20];
    const float* gb2      = (const float*)d_in[21];
    float* out = (float*)d_out;

    char* ws = (char*)d_ws;
    const size_t SZ_HB = (size_t)N_NODES * 256 * 4;     // 40.96 MB
    const size_t SZ_T  = (size_t)N_NODES * HID * 4;     // 20.48 MB
    const size_t SZ_E  = (size_t)N_EDGES * 4;           // 2.56 MB
    float* hb     = (float*)(ws);                       // [N,256] = [h | agg]
    float* P      = (float*)(ws + SZ_HB);               // [N,256]; decoder tmp2
    float* tmp1   = (float*)(ws + SZ_HB * 2);           // [N,128]
    char*  base   = ws + SZ_HB * 2 + SZ_T;
    float* radial = (float*)(base);
    int*   s_row  = (int*)  (base + SZ_E);
    int*   s_col  = (int*)  (base + SZ_E * 2);
    float* s_rad  = (float*)(base + SZ_E * 3);
    float* s_ea   = (float*)(base + SZ_E * 4);          // E x 4
    int*   rowptr = (int*)  (base + SZ_E * 8);
    int*   cnt    = (int*)  (base + SZ_E * 8 + (N_NODES + 64) * 4);

    const int* erow = edges;
    const int* ecol = edges + N_EDGES;

    radial_kernel<<<N_EDGES / 256, 256, 0, stream>>>(x, erow, ecol, radial);

    // CSR build (edges constant across layers)
    hipMemsetAsync(cnt, 0, N_NODES * 4, stream);
    hist_kernel<<<N_EDGES / 256, 256, 0, stream>>>(erow, cnt);
    scan_kernel<<<1, 1024, 0, stream>>>(cnt, rowptr);
    hipMemsetAsync(cnt, 0, N_NODES * 4, stream);
    scatter_kernel<<<N_EDGES / 256, 256, 0, stream>>>(
        erow, ecol, radial, edge_attr, rowptr, cnt, s_row, s_col, s_rad, s_ea);

    // h = h0 @ emb_w + emb_b  (into hb cols 0..127)
    gemm_kernel<<<(N_NODES + 31) / 32, 256, 0, stream>>>(
        h0, F_IN, emb_w, HID, emb_b, hb, 256, N_NODES, F_IN, HID, FLAG_BIAS);

    for (int l = 0; l < NLAYERS; ++l) {
        const float* W1   = ew1 + (size_t)l * 261 * 128;
        const float* b1   = eb1 + l * 128;
        const float* W2   = ew2 + (size_t)l * 128 * 128;
        const float* b2v  = eb2 + l * 128;
        const float* A1   = nw1 + (size_t)l * 271 * 128;
        const float* nb1v = nb1 + l * 128;
        const float* NW2  = nw2 + (size_t)l * 128 * 128;
        const float* nb2v = nb2 + l * 128;

        zero_agg_kernel<<<N_NODES * 32 / 256, 256, 0, stream>>>(hb);

        proj_kernel<<<dim3(625, 2), 256, 0, stream>>>(hb, W1, b1, P);

        edge_kernel<<<N_EDGES / 64, 256, 0, stream>>>(
            P, s_row, s_col, s_rad, s_ea, W2, b2v,
            W1 + 256 * 128, W1 + 257 * 128, hb);

        // tmp1 = silu(hb@[A;B] + h0@C + nb1)   (K = 256 + 15 fused)
        gemm64_kernel<<<625, 256, 0, stream>>>(
            hb, 256, A1, nb1v, h0, tmp1, HID, 256, FLAG_BIAS | FLAG_SILU);
        // h += tmp1@NW2 + nb2   (residual, in place on hb cols 0..127)
        gemm64_kernel<<<625, 256, 0, stream>>>(
            tmp1, HID, NW2, nb2v, nullptr, hb, 256, 128, FLAG_BIAS | FLAG_ACC);
    }

    // decoders
    gemm64_kernel<<<625, 256, 0, stream>>>(
        hb, 256, dw1, db1, nullptr, tmp1, HID, 128, FLAG_BIAS | FLAG_SILU);
    gemm64_kernel<<<625, 256, 0, stream>>>(
        tmp1, HID, dw2, db2, nullptr, P, HID, 128, FLAG_BIAS);
    gemm64_kernel<<<625, 256, 0, stream>>>(
        P, HID, gw1, gb1, nullptr, tmp1, HID, 128, FLAG_BIAS | FLAG_SILU);
    gemm_kernel<<<(N_NODES + 31) / 32, 256, 0, stream>>>(
        tmp1, HID, gw2, NOUT, gb2, out, NOUT, N_NODES, HID, NOUT, FLAG_BIAS);
}